// Round 8
// baseline (17063.611 us; speedup 1.0000x reference)
//
#include <hip/hip_runtime.h>
#include <hip/hip_bf16.h>

#define S_LEN 512
#define D_IN  64
#define HID   256
#define MLPH  64
#define D_OUT 16

// tanh via __expf; clamped so e stays finite. ~8 instrs, no branch.
__device__ __forceinline__ float fast_tanh(float v) {
    float a = fabsf(v);
    float e = __expf(fminf(2.0f * a, 40.0f));
    float r = __fdividef(e - 1.0f, e + 1.0f);
    return copysignf(r, v);
}

// One workgroup (512 thr, 8 waves) per batch element, one CU each.
// 4-barrier pipeline: iter t computes RNN-main_t (h_t, x_t[16:]) overlapped
// with MLP(h_t)=o_{t-1}; splice dot + tanh close the step.
// REGISTER BUDGET (the round-4/5 killer): 512 thr @ 2 waves/SIMD -> 256
// unified VGPR+AGPR cap. Register weights: wv 152 + w1v 32 + biases 4 = 188;
// + ~45 working set = ~233 < 256 -> no scratch spill (round-2-proven regime).
// Splice weights / W2 / W3 live in LDS (small per-step reads, padded strides).
__launch_bounds__(512, 2)
__global__ void rnn_ar_kernel(const float* __restrict__ x,
                              const float* __restrict__ W_ih,
                              const float* __restrict__ b_ih,
                              const float* __restrict__ W_hh,
                              const float* __restrict__ b_hh,
                              const float* __restrict__ W1,
                              const float* __restrict__ b1,
                              const float* __restrict__ W2,
                              const float* __restrict__ b2,
                              const float* __restrict__ W3,
                              const float* __restrict__ b3,
                              const int*   __restrict__ ps_ptr,
                              float* __restrict__ out) {
    const int b   = blockIdx.x;
    const int tid = threadIdx.x;
    const int ps  = *ps_ptr;

    // roles
    const int r     = tid >> 1;       // RNN row (0..255)
    const int q     = tid & 1;        // RNN K-half
    const int m1row = tid >> 3;       // MLP1/2 row (0..63)
    const int m1q   = tid & 7;        // MLP1/2 K-chunk (0..7)
    const int row3  = tid >> 4;       // MLP3 row (0..15) when tid<256
    const int q3    = tid & 15;       // MLP3 K-chunk

    // LDS. s_A[p] = [ x_t[16:64) (48) | h_t (256) ] combined K-vector.
    __shared__ __align__(16) float s_A[2][304];
    __shared__ __align__(16) float s_hp[2][8][36]; // h chunked for MLP1 (pad 36)
    __shared__ __align__(16) float s_wsp[256][20]; // W_ih[:,0:16) (splice w, pad 20)
    __shared__ __align__(16) float s_w2[64][68];   // W2 padded (stride 68)
    __shared__ __align__(16) float s_w3[16][68];   // W3 padded
    __shared__ __align__(16) float s_a1[MLPH];
    __shared__ __align__(16) float s_a2[MLPH];
    __shared__ __align__(16) float s_o[2][16];     // splice zone: x_t[0:16) or o_{t-1}

    // ---- register-resident weights
    // RNN combined K-vector: q=0 -> [x48 | h[0:104)], q=1 -> h[104:256)
    float4 wv[38];
    {
        const float* wih_r = W_ih + (size_t)r * D_IN;
        const float* whh_r = W_hh + (size_t)r * HID;
        if (q == 0) {
            #pragma unroll
            for (int j = 0; j < 12; ++j) wv[j] = *(const float4*)(wih_r + 16 + j * 4);
            #pragma unroll
            for (int j = 0; j < 26; ++j) wv[12 + j] = *(const float4*)(whh_r + j * 4);
        } else {
            #pragma unroll
            for (int j = 0; j < 38; ++j) wv[j] = *(const float4*)(whh_r + 104 + j * 4);
        }
    }
    float4 w1v[8];
    #pragma unroll
    for (int j = 0; j < 8; ++j)
        w1v[j] = *(const float4*)(W1 + (size_t)m1row * HID + m1q * 32 + j * 4);
    float bias_h = (q == 0) ? (b_ih[r] + b_hh[r]) : 0.f;
    float bias1  = (m1q == 0) ? b1[m1row] : 0.f;
    float bias2  = (m1q == 0) ? b2[m1row] : 0.f;
    float bias3  = (tid < 256 && q3 == 0) ? b3[row3] : 0.f;

    // ---- prologue: LDS weight fills, h0 = 0, x_0 staged, xcur = x_1
    {   // s_wsp: 1024 float4 total, 2 per thread
        #pragma unroll
        for (int k = 0; k < 2; ++k) {
            int f = tid + k * 512;              // 0..1023
            int rr = f >> 2, jj = f & 3;
            *(float4*)&s_wsp[rr][jj * 4] = *(const float4*)(W_ih + (size_t)rr * D_IN + jj * 4);
        }
        // s_w2: 1024 float4, 2 per thread
        #pragma unroll
        for (int k = 0; k < 2; ++k) {
            int f = tid + k * 512;
            int rr = f >> 4, jj = f & 15;
            *(float4*)&s_w2[rr][jj * 4] = *(const float4*)(W2 + (size_t)rr * MLPH + jj * 4);
        }
        // s_w3: 256 float4
        if (tid < 256) {
            int rr = tid >> 4, jj = tid & 15;
            *(float4*)&s_w3[rr][jj * 4] = *(const float4*)(W3 + (size_t)rr * MLPH + jj * 4);
        }
    }
    const float* xb = x + (size_t)b * S_LEN * D_IN;
    if (tid < 256) s_A[0][48 + tid] = 0.f;
    if (tid < 288) ((float*)s_hp)[tid] = 0.f;   // zeros s_hp[0]
    float4 xcur = make_float4(0, 0, 0, 0), xnxt = make_float4(0, 0, 0, 0);
    if (tid < 16) {
        float4 x0 = *(const float4*)(xb + tid * 4);
        if (tid < 4) *(float4*)&s_o[0][tid * 4] = x0;
        else         *(float4*)&s_A[0][(tid - 4) * 4] = x0;
        xcur = *(const float4*)(xb + D_IN + tid * 4);   // x_1
    }
    __syncthreads();

    float ra0, ra1, ra2, ra3;
#define RNN_CHUNKS(C0, C1)                                      \
    {                                                           \
        _Pragma("unroll")                                       \
        for (int c = (C0); c < (C1); ++c) {                     \
            float4 v = *(const float4*)(Abase + c * 4);         \
            ra0 = fmaf(wv[c].x, v.x, ra0);                      \
            ra1 = fmaf(wv[c].y, v.y, ra1);                      \
            ra2 = fmaf(wv[c].z, v.z, ra2);                      \
            ra3 = fmaf(wv[c].w, v.w, ra3);                      \
        }                                                       \
    }

    for (int t = 0; t < S_LEN; ++t) {
        const int p = t & 1;
        const float* Abase = &s_A[p][q * 152];
        ra0 = ra1 = ra2 = ra3 = 0.f;

        // ========= I1: RNN chunks 0-7 + MLP1 (o_{t-1} path) + x prefetch ===
        if (tid < 16) {
            int tn = (t + 2 < S_LEN) ? t + 2 : S_LEN - 1;
            xnxt = *(const float4*)(xb + (size_t)tn * D_IN + tid * 4);
        }
        RNN_CHUNKS(0, 8)
        {
            float m0 = 0.f, m1 = 0.f, m2 = 0.f, m3 = 0.f;
            const float* hp = &s_hp[p][m1q][0];
            #pragma unroll
            for (int j = 0; j < 8; ++j) {
                float4 v = *(const float4*)(hp + j * 4);
                m0 = fmaf(w1v[j].x, v.x, m0);
                m1 = fmaf(w1v[j].y, v.y, m1);
                m2 = fmaf(w1v[j].z, v.z, m2);
                m3 = fmaf(w1v[j].w, v.w, m3);
            }
            float m = (m0 + m1) + (m2 + m3);
            m += __shfl_xor(m, 1);
            m += __shfl_xor(m, 2);
            m += __shfl_xor(m, 4);
            if (m1q == 0) s_a1[m1row] = fmaxf(m + bias1, 0.f);
        }
        __syncthreads();

        // ========= I2: RNN chunks 8-17 + MLP2 + stage x_{t+1}[0:16) ========
        RNN_CHUNKS(8, 18)
        {
            const float* wp = &s_w2[m1row][m1q * 8];
            float4 w0 = *(const float4*)(wp);
            float4 w1 = *(const float4*)(wp + 4);
            float4 v0 = *(const float4*)&s_a1[m1q * 8];
            float4 v1 = *(const float4*)&s_a1[m1q * 8 + 4];
            float m0 = fmaf(w0.x, v0.x, 0.f);
            m0 = fmaf(w0.y, v0.y, m0);
            m0 = fmaf(w0.z, v0.z, m0);
            m0 = fmaf(w0.w, v0.w, m0);
            float m1 = fmaf(w1.x, v1.x, 0.f);
            m1 = fmaf(w1.y, v1.y, m1);
            m1 = fmaf(w1.z, v1.z, m1);
            m1 = fmaf(w1.w, v1.w, m1);
            float m = m0 + m1;
            m += __shfl_xor(m, 1);
            m += __shfl_xor(m, 2);
            m += __shfl_xor(m, 4);
            if (m1q == 0) s_a2[m1row] = fmaxf(m + bias2, 0.f);
        }
        if (tid < 4) *(float4*)&s_o[1 - p][tid * 4] = xcur;
        __syncthreads();

        // ========= I3: RNN chunks 18-29 + MLP3 -> o_{t-1}, out, splice =====
        RNN_CHUNKS(18, 30)
        if (tid < 256) {
            float4 w = *(const float4*)&s_w3[row3][q3 * 4];
            float4 v = *(const float4*)&s_a2[q3 * 4];
            float m = fmaf(w.x, v.x, 0.f);
            m = fmaf(w.y, v.y, m);
            m = fmaf(w.z, v.z, m);
            m = fmaf(w.w, v.w, m);
            m += __shfl_xor(m, 1);
            m += __shfl_xor(m, 2);
            m += __shfl_xor(m, 4);
            m += __shfl_xor(m, 8);
            if (q3 == 0) {
                float o = m + bias3;
                if (t > 0)  out[((size_t)b * S_LEN + (t - 1)) * D_OUT + row3] = o;
                if (t > ps) s_o[p][row3] = o;   // splice o_{t-1} into x_t[0:16)
            }
        }
        __syncthreads();

        // ========= I4: RNN chunks 30-37 + splice dot + tanh ================
        RNN_CHUNKS(30, 38)
        if (tid >= 4 && tid < 16)
            *(float4*)&s_A[1 - p][(tid - 4) * 4] = xcur;      // x_{t+1}[16:64)
        float accsum = (ra0 + ra1) + (ra2 + ra3);
        accsum += __shfl_xor(accsum, 1);                      // join K-halves
        if (q == 0) {
            const float* wp = &s_wsp[r][0];
            const float* ov = &s_o[p][0];
            float s0 = 0.f, s1 = 0.f, s2 = 0.f, s3 = 0.f;
            #pragma unroll
            for (int j = 0; j < 4; ++j) {
                float4 w = *(const float4*)(wp + j * 4);
                float4 v = *(const float4*)(ov + j * 4);
                s0 = fmaf(w.x, v.x, s0);
                s1 = fmaf(w.y, v.y, s1);
                s2 = fmaf(w.z, v.z, s2);
                s3 = fmaf(w.w, v.w, s3);
            }
            float h = fast_tanh(accsum + ((s0 + s1) + (s2 + s3)) + bias_h);
            s_A[1 - p][48 + r] = h;                 // next RNN step input
            s_hp[1 - p][r >> 5][r & 31] = h;        // chunked copy for MLP1
        }
        if (tid < 16) xcur = xnxt;
        __syncthreads();
    }

    // ========= epilogue: o_{S-1} = mlp(h_S); h_S is in buffers p = 0 =======
    {
        const int p = 0;
        {
            float m0 = 0.f, m1 = 0.f, m2 = 0.f, m3 = 0.f;
            const float* hp = &s_hp[p][m1q][0];
            #pragma unroll
            for (int j = 0; j < 8; ++j) {
                float4 v = *(const float4*)(hp + j * 4);
                m0 = fmaf(w1v[j].x, v.x, m0);
                m1 = fmaf(w1v[j].y, v.y, m1);
                m2 = fmaf(w1v[j].z, v.z, m2);
                m3 = fmaf(w1v[j].w, v.w, m3);
            }
            float m = (m0 + m1) + (m2 + m3);
            m += __shfl_xor(m, 1);
            m += __shfl_xor(m, 2);
            m += __shfl_xor(m, 4);
            if (m1q == 0) s_a1[m1row] = fmaxf(m + bias1, 0.f);
        }
        __syncthreads();
        {
            const float* wp = &s_w2[m1row][m1q * 8];
            float4 w0 = *(const float4*)(wp);
            float4 w1 = *(const float4*)(wp + 4);
            float4 v0 = *(const float4*)&s_a1[m1q * 8];
            float4 v1 = *(const float4*)&s_a1[m1q * 8 + 4];
            float m0 = fmaf(w0.x, v0.x, 0.f);
            m0 = fmaf(w0.y, v0.y, m0);
            m0 = fmaf(w0.z, v0.z, m0);
            m0 = fmaf(w0.w, v0.w, m0);
            float m1 = fmaf(w1.x, v1.x, 0.f);
            m1 = fmaf(w1.y, v1.y, m1);
            m1 = fmaf(w1.z, v1.z, m1);
            m1 = fmaf(w1.w, v1.w, m1);
            float m = m0 + m1;
            m += __shfl_xor(m, 1);
            m += __shfl_xor(m, 2);
            m += __shfl_xor(m, 4);
            if (m1q == 0) s_a2[m1row] = fmaxf(m + bias2, 0.f);
        }
        __syncthreads();
        if (tid < 256) {
            float4 w = *(const float4*)&s_w3[row3][q3 * 4];
            float4 v = *(const float4*)&s_a2[q3 * 4];
            float m = fmaf(w.x, v.x, 0.f);
            m = fmaf(w.y, v.y, m);
            m = fmaf(w.z, v.z, m);
            m = fmaf(w.w, v.w, m);
            m += __shfl_xor(m, 1);
            m += __shfl_xor(m, 2);
            m += __shfl_xor(m, 4);
            m += __shfl_xor(m, 8);
            if (q3 == 0)
                out[((size_t)b * S_LEN + (S_LEN - 1)) * D_OUT + row3] = m + bias3;
        }
    }
#undef RNN_CHUNKS
}

extern "C" void kernel_launch(void* const* d_in, const int* in_sizes, int n_in,
                              void* d_out, int out_size, void* d_ws, size_t ws_size,
                              hipStream_t stream) {
    (void)in_sizes; (void)n_in; (void)d_ws; (void)ws_size; (void)out_size;
    const float* x    = (const float*)d_in[0];
    const float* W_ih = (const float*)d_in[1];
    const float* bih  = (const float*)d_in[2];
    const float* W_hh = (const float*)d_in[3];
    const float* bhh  = (const float*)d_in[4];
    const float* W1   = (const float*)d_in[5];
    const float* b1   = (const float*)d_in[6];
    const float* W2   = (const float*)d_in[7];
    const float* b2   = (const float*)d_in[8];
    const float* W3   = (const float*)d_in[9];
    const float* b3   = (const float*)d_in[10];
    const int*   ps   = (const int*)d_in[11];
    float* out = (float*)d_out;

    rnn_ar_kernel<<<dim3(256), dim3(512), 0, stream>>>(
        x, W_ih, bih, W_hh, bhh, W1, b1, W2, b2, W3, b3, ps, out);
}

// Round 9
// 8099.496 us; speedup vs baseline: 2.1067x; 2.1067x over previous
//
#include <hip/hip_runtime.h>
#include <hip/hip_bf16.h>

#define S_LEN 512
#define D_IN  64
#define HID   256
#define MLPH  64
#define D_OUT 16

// tanh via __expf; clamped so e stays finite. ~8 instrs, no branch.
__device__ __forceinline__ float fast_tanh(float v) {
    float a = fabsf(v);
    float e = __expf(fminf(2.0f * a, 40.0f));
    float r = __fdividef(e - 1.0f, e + 1.0f);
    return copysignf(r, v);
}

// One workgroup (512 thr, 8 waves) per batch element, one CU each.
// 4-barrier pipeline: iter t computes RNN-main_t overlapped with MLP(h_t)=o_{t-1}.
// SPILL LESSON (rounds 4/5/8): per-thread weight arrays must be initialized
// with BRANCH-FREE, uniformly-unrolled loads (address arithmetic only), or the
// compiler parks them in scratch and re-reads every step (15 GB/launch!).
// This kernel mirrors round-2's proven-no-spill init shape exactly:
//   whh4[32] <- W_hh + r*256 + q*128   (uniform)
//   wih4[6]  <- W_ih + r*64 + 16+q*24  (uniform)
// Register weights: 128+24+32+8+4(+4 bias) = 200 floats < round-2's 208.
__launch_bounds__(512, 2)
__global__ void rnn_ar_kernel(const float* __restrict__ x,
                              const float* __restrict__ W_ih,
                              const float* __restrict__ b_ih,
                              const float* __restrict__ W_hh,
                              const float* __restrict__ b_hh,
                              const float* __restrict__ W1,
                              const float* __restrict__ b1,
                              const float* __restrict__ W2,
                              const float* __restrict__ b2,
                              const float* __restrict__ W3,
                              const float* __restrict__ b3,
                              const int*   __restrict__ ps_ptr,
                              float* __restrict__ out) {
    const int b   = blockIdx.x;
    const int tid = threadIdx.x;
    const int ps  = *ps_ptr;

    // roles
    const int r     = tid >> 1;       // RNN row (0..255)
    const int q     = tid & 1;        // RNN K-half (intra-wave pair -> shfl join)
    const int m1row = tid >> 3;       // MLP1/2 row (0..63)
    const int m1q   = tid & 7;        // MLP1/2 K-chunk (0..7)
    const int row3  = tid >> 4;       // MLP3 row (0..15) when tid<256
    const int q3    = tid & 15;       // MLP3 K-chunk

    // LDS. s_A[p] = [ x_t[16:64) (48) | h_t (256) ].
    __shared__ __align__(16) float s_A[2][304];
    __shared__ __align__(16) float s_hp[2][8][36]; // h chunked for MLP1 (broadcast reads)
    __shared__ __align__(16) float s_wsp[256][20]; // W_ih[:,0:16) splice weights
    __shared__ __align__(16) float s_a1[MLPH];
    __shared__ __align__(16) float s_a2[MLPH];
    __shared__ __align__(16) float s_o[2][16];     // splice zone: x_t[0:16) or o_{t-1}

    // ---- register weights, ALL branch-free uniform unrolled inits
    float4 whh4[32];                  // W_hh[r, q*128 .. +128)
    {
        const float4* s4 = (const float4*)(W_hh + (size_t)r * HID + q * 128);
        #pragma unroll
        for (int j = 0; j < 32; ++j) whh4[j] = s4[j];
    }
    float4 wih4[6];                   // W_ih[r, 16+q*24 .. +24)
    {
        const float4* s4 = (const float4*)(W_ih + (size_t)r * D_IN + 16 + q * 24);
        #pragma unroll
        for (int j = 0; j < 6; ++j) wih4[j] = s4[j];
    }
    float4 w1v[8];                    // W1[m1row, m1q*32 .. +32)
    #pragma unroll
    for (int j = 0; j < 8; ++j)
        w1v[j] = *(const float4*)(W1 + (size_t)m1row * HID + m1q * 32 + j * 4);
    float4 w2v[2];                    // W2[m1row, m1q*8 .. +8)
    w2v[0] = *(const float4*)(W2 + (size_t)m1row * MLPH + m1q * 8);
    w2v[1] = *(const float4*)(W2 + (size_t)m1row * MLPH + m1q * 8 + 4);
    float4 w3v =                      // W3[row3&15, q3*4 .. +4)
        *(const float4*)(W3 + (size_t)(row3 & 15) * MLPH + q3 * 4);
    // biases: unconditional loads (uniform), predicated USE only
    float bias_h = b_ih[r] + b_hh[r];
    float bias1  = b1[m1row];
    float bias2  = b2[m1row];
    float bias3  = b3[row3 & 15];

    // ---- prologue: splice weights to LDS, h0 = 0, x_0 staged, xcur = x_1
    {
        #pragma unroll
        for (int k = 0; k < 2; ++k) {
            int f = tid + k * 512;              // 0..1023
            int rr = f >> 2, jj = f & 3;
            *(float4*)&s_wsp[rr][jj * 4] = *(const float4*)(W_ih + (size_t)rr * D_IN + jj * 4);
        }
    }
    const float* xb = x + (size_t)b * S_LEN * D_IN;
    if (tid < 256) s_A[0][48 + tid] = 0.f;
    if (tid < 288) ((float*)s_hp)[tid] = 0.f;   // zeros s_hp[0]
    float4 xcur = make_float4(0, 0, 0, 0), xnxt = make_float4(0, 0, 0, 0);
    if (tid < 16) {
        float4 x0 = *(const float4*)(xb + tid * 4);
        if (tid < 4) *(float4*)&s_o[0][tid * 4] = x0;
        else         *(float4*)&s_A[0][(tid - 4) * 4] = x0;
        xcur = *(const float4*)(xb + D_IN + tid * 4);   // x_1
    }
    __syncthreads();

    float ra0, ra1, ra2, ra3;
#define RNN_H(C0, C1)                                           \
    {                                                           \
        _Pragma("unroll")                                       \
        for (int c = (C0); c < (C1); ++c) {                     \
            float4 v = *(const float4*)(hbase + c * 4);         \
            ra0 = fmaf(whh4[c].x, v.x, ra0);                    \
            ra1 = fmaf(whh4[c].y, v.y, ra1);                    \
            ra2 = fmaf(whh4[c].z, v.z, ra2);                    \
            ra3 = fmaf(whh4[c].w, v.w, ra3);                    \
        }                                                       \
    }

    for (int t = 0; t < S_LEN; ++t) {
        const int p = t & 1;
        const float* hbase = &s_A[p][48 + q * 128];
        const float* xbase = &s_A[p][q * 24];
        ra0 = ra1 = ra2 = ra3 = 0.f;

        // ========= I1: RNN whh 0-10 + MLP1 (o_{t-1} path) + x prefetch =====
        if (tid < 16) {
            int tn = (t + 2 < S_LEN) ? t + 2 : S_LEN - 1;
            xnxt = *(const float4*)(xb + (size_t)tn * D_IN + tid * 4);
        }
        RNN_H(0, 10)
        {
            float m0 = 0.f, m1 = 0.f, m2 = 0.f, m3 = 0.f;
            const float* hp = &s_hp[p][m1q][0];
            #pragma unroll
            for (int j = 0; j < 8; ++j) {
                float4 v = *(const float4*)(hp + j * 4);
                m0 = fmaf(w1v[j].x, v.x, m0);
                m1 = fmaf(w1v[j].y, v.y, m1);
                m2 = fmaf(w1v[j].z, v.z, m2);
                m3 = fmaf(w1v[j].w, v.w, m3);
            }
            float m = (m0 + m1) + (m2 + m3);
            m += __shfl_xor(m, 1);
            m += __shfl_xor(m, 2);
            m += __shfl_xor(m, 4);
            if (m1q == 0) s_a1[m1row] = fmaxf(m + bias1, 0.f);
        }
        __syncthreads();

        // ========= I2: RNN whh 10-20 + MLP2 + stage x_{t+1}[0:16) ==========
        RNN_H(10, 20)
        {
            float4 v0 = *(const float4*)&s_a1[m1q * 8];
            float4 v1 = *(const float4*)&s_a1[m1q * 8 + 4];
            float m0 = fmaf(w2v[0].x, v0.x, 0.f);
            m0 = fmaf(w2v[0].y, v0.y, m0);
            m0 = fmaf(w2v[0].z, v0.z, m0);
            m0 = fmaf(w2v[0].w, v0.w, m0);
            float m1 = fmaf(w2v[1].x, v1.x, 0.f);
            m1 = fmaf(w2v[1].y, v1.y, m1);
            m1 = fmaf(w2v[1].z, v1.z, m1);
            m1 = fmaf(w2v[1].w, v1.w, m1);
            float m = m0 + m1;
            m += __shfl_xor(m, 1);
            m += __shfl_xor(m, 2);
            m += __shfl_xor(m, 4);
            if (m1q == 0) s_a2[m1row] = fmaxf(m + bias2, 0.f);
        }
        if (tid < 4) *(float4*)&s_o[1 - p][tid * 4] = xcur;
        __syncthreads();

        // ========= I3: RNN whh 20-30 + MLP3 -> o_{t-1}, out, splice ========
        RNN_H(20, 30)
        if (tid < 256) {
            float4 v = *(const float4*)&s_a2[q3 * 4];
            float m = fmaf(w3v.x, v.x, 0.f);
            m = fmaf(w3v.y, v.y, m);
            m = fmaf(w3v.z, v.z, m);
            m = fmaf(w3v.w, v.w, m);
            m += __shfl_xor(m, 1);
            m += __shfl_xor(m, 2);
            m += __shfl_xor(m, 4);
            m += __shfl_xor(m, 8);
            if (q3 == 0) {
                float o = m + bias3;
                if (t > 0)  out[((size_t)b * S_LEN + (t - 1)) * D_OUT + row3] = o;
                if (t > ps) s_o[p][row3] = o;   // splice o_{t-1} into x_t[0:16)
            }
        }
        __syncthreads();

        // ========= I4: RNN whh 30-32 + wih 0-6 + splice dot + tanh =========
        RNN_H(30, 32)
        {
            #pragma unroll
            for (int j = 0; j < 6; ++j) {
                float4 v = *(const float4*)(xbase + j * 4);
                ra0 = fmaf(wih4[j].x, v.x, ra0);
                ra1 = fmaf(wih4[j].y, v.y, ra1);
                ra2 = fmaf(wih4[j].z, v.z, ra2);
                ra3 = fmaf(wih4[j].w, v.w, ra3);
            }
        }
        if (tid >= 4 && tid < 16)
            *(float4*)&s_A[1 - p][(tid - 4) * 4] = xcur;      // x_{t+1}[16:64)
        float accsum = (ra0 + ra1) + (ra2 + ra3);
        accsum += __shfl_xor(accsum, 1);                      // join K-halves
        if (q == 0) {
            const float* wp = &s_wsp[r][0];
            const float* ov = &s_o[p][0];
            float s0 = 0.f, s1 = 0.f, s2 = 0.f, s3 = 0.f;
            #pragma unroll
            for (int j = 0; j < 4; ++j) {
                float4 w = *(const float4*)(wp + j * 4);
                float4 v = *(const float4*)(ov + j * 4);
                s0 = fmaf(w.x, v.x, s0);
                s1 = fmaf(w.y, v.y, s1);
                s2 = fmaf(w.z, v.z, s2);
                s3 = fmaf(w.w, v.w, s3);
            }
            float h = fast_tanh(accsum + ((s0 + s1) + (s2 + s3)) + bias_h);
            s_A[1 - p][48 + r] = h;                 // next RNN step input
            s_hp[1 - p][r >> 5][r & 31] = h;        // chunked copy for MLP1
        }
        if (tid < 16) xcur = xnxt;
        __syncthreads();
    }

    // ========= epilogue: o_{S-1} = mlp(h_S); h_S is in buffers p = 0 =======
    {
        const int p = 0;
        {
            float m0 = 0.f, m1 = 0.f, m2 = 0.f, m3 = 0.f;
            const float* hp = &s_hp[p][m1q][0];
            #pragma unroll
            for (int j = 0; j < 8; ++j) {
                float4 v = *(const float4*)(hp + j * 4);
                m0 = fmaf(w1v[j].x, v.x, m0);
                m1 = fmaf(w1v[j].y, v.y, m1);
                m2 = fmaf(w1v[j].z, v.z, m2);
                m3 = fmaf(w1v[j].w, v.w, m3);
            }
            float m = (m0 + m1) + (m2 + m3);
            m += __shfl_xor(m, 1);
            m += __shfl_xor(m, 2);
            m += __shfl_xor(m, 4);
            if (m1q == 0) s_a1[m1row] = fmaxf(m + bias1, 0.f);
        }
        __syncthreads();
        {
            float4 v0 = *(const float4*)&s_a1[m1q * 8];
            float4 v1 = *(const float4*)&s_a1[m1q * 8 + 4];
            float m0 = fmaf(w2v[0].x, v0.x, 0.f);
            m0 = fmaf(w2v[0].y, v0.y, m0);
            m0 = fmaf(w2v[0].z, v0.z, m0);
            m0 = fmaf(w2v[0].w, v0.w, m0);
            float m1 = fmaf(w2v[1].x, v1.x, 0.f);
            m1 = fmaf(w2v[1].y, v1.y, m1);
            m1 = fmaf(w2v[1].z, v1.z, m1);
            m1 = fmaf(w2v[1].w, v1.w, m1);
            float m = m0 + m1;
            m += __shfl_xor(m, 1);
            m += __shfl_xor(m, 2);
            m += __shfl_xor(m, 4);
            if (m1q == 0) s_a2[m1row] = fmaxf(m + bias2, 0.f);
        }
        __syncthreads();
        if (tid < 256) {
            float4 v = *(const float4*)&s_a2[q3 * 4];
            float m = fmaf(w3v.x, v.x, 0.f);
            m = fmaf(w3v.y, v.y, m);
            m = fmaf(w3v.z, v.z, m);
            m = fmaf(w3v.w, v.w, m);
            m += __shfl_xor(m, 1);
            m += __shfl_xor(m, 2);
            m += __shfl_xor(m, 4);
            m += __shfl_xor(m, 8);
            if (q3 == 0)
                out[((size_t)b * S_LEN + (S_LEN - 1)) * D_OUT + row3] = m + bias3;
        }
    }
#undef RNN_H
}

extern "C" void kernel_launch(void* const* d_in, const int* in_sizes, int n_in,
                              void* d_out, int out_size, void* d_ws, size_t ws_size,
                              hipStream_t stream) {
    (void)in_sizes; (void)n_in; (void)d_ws; (void)ws_size; (void)out_size;
    const float* x    = (const float*)d_in[0];
    const float* W_ih = (const float*)d_in[1];
    const float* bih  = (const float*)d_in[2];
    const float* W_hh = (const float*)d_in[3];
    const float* bhh  = (const float*)d_in[4];
    const float* W1   = (const float*)d_in[5];
    const float* b1   = (const float*)d_in[6];
    const float* W2   = (const float*)d_in[7];
    const float* b2   = (const float*)d_in[8];
    const float* W3   = (const float*)d_in[9];
    const float* b3   = (const float*)d_in[10];
    const int*   ps   = (const int*)d_in[11];
    float* out = (float*)d_out;

    rnn_ar_kernel<<<dim3(256), dim3(512), 0, stream>>>(
        x, W_ih, bih, W_hh, bhh, W1, b1, W2, b2, W3, b3, ps, out);
}